// Round 5
// baseline (288.364 us; speedup 1.0000x reference)
//
#include <hip/hip_runtime.h>

#define N 256
#define NB 256                // one block per LINE (one wave per block, one block per CU)
#define NT 64                 // single wave
#define LAM 0.05f             // step = ALPHA/2
#define TWOLAM (2.0f * LAM)
#define FOURLAM (4.0f * LAM)
#define MAXIT 35
#define TOL 0.01f
#define SLOTSTRIDE 2          // fallback kernel: 16 B per line slot
#define POLLBUDGET (1 << 17)  // hang-proofing: ~5 ms of probes, >>1000x legit skew

typedef unsigned long long u64;

// broadcast-read one lane's register (lane index is wave-uniform -> v_readlane)
__device__ __forceinline__ float rlane(float v, int lane) {
    return __int_as_float(__builtin_amdgcn_readlane(__float_as_int(v), lane));
}

// agent-scope (L2-bypassing) accesses for cross-wave-communicated arrays.
__device__ __forceinline__ void gstore(float* p, float v) {
    __hip_atomic_store(p, v, __ATOMIC_RELAXED, __HIP_MEMORY_SCOPE_AGENT);
}
__device__ __forceinline__ u64 ald(const u64* p) {
    return __hip_atomic_load(p, __ATOMIC_RELAXED, __HIP_MEMORY_SCOPE_AGENT);
}
__device__ __forceinline__ void ast(u64* p, u64 v) {
    __hip_atomic_store(p, v, __ATOMIC_RELAXED, __HIP_MEMORY_SCOPE_AGENT);
}

// Scattered COLUMN read of a row-major float matrix (X at it=0 only).
__device__ __forceinline__ void gload_col(const float* mat, int c, int lane, float& a,
                                          float& b, float& d, float& e) {
    const float* p0 = mat + (size_t)lane * N + c;
    const float* p1 = p0 + 64 * N;
    const float* p2 = p0 + 128 * N;
    const float* p3 = p0 + 192 * N;
    asm volatile("global_load_dword %0, %4, off sc0 sc1\n\t"
                 "global_load_dword %1, %5, off sc0 sc1\n\t"
                 "global_load_dword %2, %6, off sc0 sc1\n\t"
                 "global_load_dword %3, %7, off sc0 sc1\n\t"
                 "s_waitcnt vmcnt(0)"
                 : "=&v"(a), "=&v"(b), "=&v"(d), "=&v"(e)
                 : "v"(p0), "v"(p1), "v"(p2), "v"(p3)
                 : "memory");
}

// 256-float line distributed over the wave: element k lives in lane (k&63), reg (k>>6)
struct Dist { float r0, r1, r2, r3; };

// branchless fetch: 4 independent readlanes + 2 uniform selects
__device__ __forceinline__ float dfetch(const Dist& d, int k) {
    const int lane = k & 63;
    const int sel = k >> 6;
    float a = rlane(d.r0, lane);
    float b = rlane(d.r1, lane);
    float c = rlane(d.r2, lane);
    float e = rlane(d.r3, lane);
    float ab = (sel & 1) ? b : a;
    float ce = (sel & 1) ? e : c;
    return (sel & 2) ? ce : ab;
}

// O(1) segment flush: o[j] = val for j in [lo, hi]
__device__ __forceinline__ void flushseg(Dist& o, int lo, int hi, float val, int lane) {
    const unsigned len = (unsigned)(hi - lo);
    const int base = lane - lo;
    o.r0 = ((unsigned)(base      ) <= len) ? val : o.r0;
    o.r1 = ((unsigned)(base + 64 ) <= len) ? val : o.r1;
    o.r2 = ((unsigned)(base + 128) <= len) ? val : o.r2;
    o.r3 = ((unsigned)(base + 192) <= len) ? val : o.r3;
}

// scalar 4-way select of a 64-bit mask (s_cselect_b64)
__device__ __forceinline__ u64 sel4(u64 a, u64 b, u64 c, u64 d, int r) {
    u64 ab = (r & 1) ? b : a;
    u64 cd = (r & 1) ? d : c;
    return (r & 2) ? cd : ab;
}

// full-wave max of nonneg-float-as-uint via DPP ladder; verified bitwise R1-R3.
__device__ __forceinline__ unsigned wredmax(unsigned x) {
    unsigned t;
    t = (unsigned)__builtin_amdgcn_update_dpp(0, (int)x, 0x111, 0xf, 0xf, true); x = x > t ? x : t; // row_shr:1
    t = (unsigned)__builtin_amdgcn_update_dpp(0, (int)x, 0x112, 0xf, 0xf, true); x = x > t ? x : t; // row_shr:2
    t = (unsigned)__builtin_amdgcn_update_dpp(0, (int)x, 0x114, 0xf, 0xf, true); x = x > t ? x : t; // row_shr:4
    t = (unsigned)__builtin_amdgcn_update_dpp(0, (int)x, 0x118, 0xf, 0xf, true); x = x > t ? x : t; // row_shr:8
    t = (unsigned)__builtin_amdgcn_update_dpp(0, (int)x, 0x142, 0xf, 0xf, true); x = x > t ? x : t; // row_bcast:15
    t = (unsigned)__builtin_amdgcn_update_dpp(0, (int)x, 0x143, 0xf, 0xf, true); x = x > t ? x : t; // row_bcast:31
    return (unsigned)__builtin_amdgcn_readlane((int)x, 63);
}

// ===================== tagged-data transport (fused barrier) =================
// Element = {float bits : high 32, seq : low 32}, one naturally-aligned 64-bit
// atom -> tag-implies-data with NO fences and NO drain.
// HANG-PROOFING (R4 lesson): every poll is budgeted. A protocol bug now
// surfaces as a wrong-result failure (diagnosable), never a dead container.

// Poll-read column c of a row-major tagged matrix until all 4 own elements
// carry tag >= seq (or budget exhausts). Software-pipelined.
__device__ __forceinline__ void pollcol(const u64* m, int c, unsigned seq, int lane, Dist& v) {
    const u64* p0 = m + (size_t)lane * N + c;
    const u64* p1 = p0 + 64 * N;
    const u64* p2 = p0 + 128 * N;
    const u64* p3 = p0 + 192 * N;
    u64 f0 = ald(p0), f1 = ald(p1), f2 = ald(p2), f3 = ald(p3);
    int spin = 0;
    for (;;) {
        u64 g0 = ald(p0), g1 = ald(p1), g2 = ald(p2), g3 = ald(p3);
        const bool ok = ((unsigned)f0 >= seq) & ((unsigned)f1 >= seq) &
                        ((unsigned)f2 >= seq) & ((unsigned)f3 >= seq);
        if (__all((int)ok)) break;
        if (__builtin_expect(++spin > POLLBUDGET, 0)) break;   // terminate, surface as bad data
        f0 = g0; f1 = g1; f2 = g2; f3 = g3;
    }
    v.r0 = __uint_as_float((unsigned)(f0 >> 32));
    v.r1 = __uint_as_float((unsigned)(f1 >> 32));
    v.r2 = __uint_as_float((unsigned)(f2 >> 32));
    v.r3 = __uint_as_float((unsigned)(f3 >> 32));
}

// Coalesced tagged row store (fire-and-forget; no drain needed — posted stores
// drain autonomously; consumers synchronize on the tags, not on vmcnt).
__device__ __forceinline__ void storerow(u64* m, int row, unsigned seq, const Dist& o, int lane) {
    u64* r = m + (size_t)row * N;
    ast(r + lane,       ((u64)__float_as_uint(o.r0) << 32) | (u64)seq);
    ast(r + lane + 64,  ((u64)__float_as_uint(o.r1) << 32) | (u64)seq);
    ast(r + lane + 128, ((u64)__float_as_uint(o.r2) << 32) | (u64)seq);
    ast(r + lane + 192, ((u64)__float_as_uint(o.r3) << 32) | (u64)seq);
}

// ============================================================================
// Condat's exact 1D TV prox (verified structure — UNCHANGED since the 213 µs
// kernel). R1 lesson: with 1 wave/SIMD, program order == critical path; no
// speculative work ahead of the un/ux -> compare -> branch chain.
__device__ void tv1d_scan(const Dist& v, Dist& o, const int lane)
{
    const float lam = LAM, mlam = -LAM, twolam = TWOLAM;

    Dist vnx;                                    // vnx[j] = v[j+1] for j<255; vnx[255] = v[255]
    {
        float a0 = __shfl_down(v.r0, 1), a1 = __shfl_down(v.r1, 1);
        float a2 = __shfl_down(v.r2, 1), a3 = __shfl_down(v.r3, 1);
        const bool hi = (lane == 63);
        vnx.r0 = hi ? rlane(v.r1, 0) : a0;
        vnx.r1 = hi ? rlane(v.r2, 0) : a1;
        vnx.r2 = hi ? rlane(v.r3, 0) : a2;
        vnx.r3 = hi ? v.r3 : a3;
    }
    Dist d;
    d.r0 = vnx.r0 - v.r0;  d.r1 = vnx.r1 - v.r1;
    d.r2 = vnx.r2 - v.r2;  d.r3 = vnx.r3 - v.r3;
    const unsigned lambits = __float_as_uint(lam);
    Dist sl;                                     // sl[j] = sign(d[j]) * lam
    sl.r0 = __uint_as_float((__float_as_uint(d.r0) & 0x80000000u) | lambits);
    sl.r1 = __uint_as_float((__float_as_uint(d.r1) & 0x80000000u) | lambits);
    sl.r2 = __uint_as_float((__float_as_uint(d.r2) & 0x80000000u) | lambits);
    sl.r3 = __uint_as_float((__float_as_uint(d.r3) & 0x80000000u) | lambits);
    Dist slp;                                    // slp[j] = sl[j-1], slp[0] = 0
    {
        float b0 = __shfl_up(sl.r0, 1), b1 = __shfl_up(sl.r1, 1);
        float b2 = __shfl_up(sl.r2, 1), b3 = __shfl_up(sl.r3, 1);
        const bool lo = (lane == 0);
        slp.r0 = lo ? 0.0f : b0;
        slp.r1 = lo ? rlane(sl.r0, 63) : b1;
        slp.r2 = lo ? rlane(sl.r1, 63) : b2;
        slp.r3 = lo ? rlane(sl.r2, 63) : b3;
    }
    Dist e, g;                                   // e[j]=v+sl-slp; g[j]=v-lam-slp
    {
        float t0 = v.r0 - slp.r0, t1 = v.r1 - slp.r1, t2 = v.r2 - slp.r2, t3 = v.r3 - slp.r3;
        e.r0 = t0 + sl.r0;  e.r1 = t1 + sl.r1;  e.r2 = t2 + sl.r2;  e.r3 = t3 + sl.r3;
        g.r0 = t0 - lam;    g.r1 = t1 - lam;    g.r2 = t2 - lam;    g.r3 = t3 - lam;
    }
    const u64 S0 = __ballot(d.r0 < 0.0f);
    const u64 S1 = __ballot(d.r1 < 0.0f);
    const u64 S2 = __ballot(d.r2 < 0.0f);
    const u64 S3 = __ballot(d.r3 < 0.0f);
    const u64 B20 = __ballot(fabsf(d.r0) > TWOLAM);
    const u64 B21 = __ballot(fabsf(d.r1) > TWOLAM);
    const u64 B22 = __ballot(fabsf(d.r2) > TWOLAM);
    const u64 B23 = __ballot(fabsf(d.r3) > TWOLAM);
    const u64 B40 = __ballot(fabsf(d.r0) > FOURLAM);
    const u64 B41 = __ballot(fabsf(d.r1) > FOURLAM);
    const u64 B42 = __ballot(fabsf(d.r2) > FOURLAM);
    const u64 B43 = __ballot(fabsf(d.r3) > FOURLAM);
    const u64 Sp0 = (S0 << 1);
    const u64 Sp1 = (S1 << 1) | (S0 >> 63);
    const u64 Sp2 = (S2 << 1) | (S1 >> 63);
    const u64 Sp3 = (S3 << 1) | (S2 >> 63);
    const u64 NF0 = ~(B40 | (B20 & ~(S0 ^ Sp0)));
    const u64 NF1 = ~(B41 | (B21 & ~(S1 ^ Sp1)));
    const u64 NF2 = ~(B42 | (B22 & ~(S2 ^ Sp2)));
    const u64 NF3 = ~((B43 | (B23 & ~(S3 ^ Sp3))) & 0x7FFFFFFFFFFFFFFFull);
    const u64 FNn0 = (S0 & B20) | (~S0 & B40);
    const u64 FNn1 = (S1 & B21) | (~S1 & B41);
    const u64 FNn2 = (S2 & B22) | (~S2 & B42);
    const u64 FNn3 = (S3 & B23) | (~S3 & B43);
    const u64 FNp0 = (~S0 & B20) | (S0 & B40);
    const u64 FNp1 = (~S1 & B21) | (S1 & B41);
    const u64 FNp2 = (~S2 & B22) | (S2 & B42);
    const u64 FNp3 = (~S3 & B23) | (S3 & B43);
    const int initFF = (int)(B40 & 1ull);

    auto firstnf = [&](int jmin) -> int {
        const int w = jmin >> 6;
        u64 m = sel4(NF0, NF1, NF2, NF3, w) >> (jmin & 63);
        if (m) return jmin + (int)__builtin_ctzll(m);
        u64 m1 = (w < 1) ? NF1 : 0ull;
        u64 m2 = (w < 2) ? NF2 : 0ull;
        if (m1) return 64 + (int)__builtin_ctzll(m1);
        if (m2) return 128 + (int)__builtin_ctzll(m2);
        return 192 + (int)__builtin_ctzll(NF3);
    };

    auto trigbit = [&](int kk, int neg) -> int {
        const int w = kk >> 6;
        const u64 m = neg ? sel4(FNn0, FNn1, FNn2, FNn3, w)
                          : sel4(FNp0, FNp1, FNp2, FNp3, w);
        return (int)((m >> (kk & 63)) & 1ull);
    };

    int k = 0, k0 = 0, km = 0, kp = 0;
    float umin = lam, umax = mlam;
    const float v0 = rlane(v.r0, 0);
    float vmin = v0 - lam, vmax = v0 + lam;
    float flen = 1.0f;
    float rnext = 0.5f;
    float vn1 = rlane(vnx.r0, 0);

    auto fastfwd = [&]() {
        const int K1 = firstnf(k + 1);
        const int sneg = (int)((sel4(S0, S1, S2, S3, k >> 6) >> (k & 63)) & 1ull);
        flushseg(o, k, k, sneg ? vmin : vmax, lane);
        if (K1 > k + 1) {
            const int lo = k + 1;
            const unsigned len = (unsigned)(K1 - 1 - lo);
            const int base = lane - lo;
            o.r0 = ((unsigned)(base      ) <= len) ? e.r0 : o.r0;
            o.r1 = ((unsigned)(base + 64 ) <= len) ? e.r1 : o.r1;
            o.r2 = ((unsigned)(base + 128) <= len) ? e.r2 : o.r2;
            o.r3 = ((unsigned)(base + 192) <= len) ? e.r3 : o.r3;
        }
        k = K1; k0 = K1; km = K1; kp = K1;
        vmin = dfetch(g, K1);
        vmax = vmin + twolam;
        umin = lam; umax = mlam;
        flen = 1.0f; rnext = 0.5f;
        vn1 = dfetch(vnx, K1);
    };

    auto do_step = [&]() {
        const float un = umin + vn1 - vmin;
        const float ux = umax + vn1 - vmax;
        const bool neg = un < mlam;
        const bool pos = ux > lam;
        const int wn = (k + 1) >> 6, bn = (k + 1) & 63;
        const int tn = (int)((sel4(FNn0, FNn1, FNn2, FNn3, wn) >> bn) & 1ull);
        const int tp = (int)((sel4(FNp0, FNp1, FNp2, FNp3, wn) >> bn) & 1ull);
        if (__builtin_expect((int)(neg | pos), 1)) {          // JUMP
            const float fval = neg ? vmin : vmax;
            const int   fhi  = neg ? km : kp;
            flushseg(o, k0, fhi, fval, lane);
            const int k0n = fhi + 1;
            float vstar;
            int trig;
            if (__builtin_expect((int)(k0n <= k), 0)) {       // rewind (rare)
                vstar = dfetch(v, k0n);
                trig = trigbit(k0n, (int)neg);
            } else {
                vstar = vn1;
                trig = neg ? tn : tp;
            }
            k = k0n; k0 = k0n; km = k0n; kp = k0n;
            vmin = neg ? vstar : vstar - twolam;
            vmax = vmin + twolam;
            umin = lam; umax = mlam;
            flen = 1.0f; rnext = 0.5f;
            if (k < N - 1 && trig) {
                fastfwd();
            } else {
                vn1 = dfetch(vnx, k);
            }
        } else {                                              // no jump (predicated)
            k++;
            const float r = rnext;
            flen += 1.0f;
            const bool cmin = (un >= lam);
            const bool cmax = (ux <= mlam);
            vmin = cmin ? fmaf(un - lam, r, vmin) : vmin;
            km   = cmin ? k : km;
            umin = cmin ? lam : un;
            vmax = cmax ? fmaf(ux + lam, r, vmax) : vmax;
            kp   = cmax ? k : kp;
            umax = cmax ? mlam : ux;
            vn1 = dfetch(vnx, k);
            rnext = __builtin_amdgcn_rcpf(flen + 1.0f);
        }
    };

    if (initFF) fastfwd();

    for (;;) {
        while (k < N - 1) {
            do_step();
            if (k >= N - 1) break;
            do_step();
        }
        for (;;) {
            if (umin < 0.0f) {
                flushseg(o, k0, km, vmin, lane);
                k0 = km + 1;
                if (k0 > N - 1) return;
                km = k = k0;
                vmin = dfetch(v, k0);
                umin = lam;
                umax = vmin + lam - vmax;
                flen = 1.0f;
            } else if (umax > 0.0f) {
                flushseg(o, k0, kp, vmax, lane);
                k0 = kp + 1;
                if (k0 > N - 1) return;
                kp = k = k0;
                vmax = dfetch(v, k0);
                umax = mlam;
                umin = vmax - lam - vmin;
                flen = 1.0f;
            } else {
                vmin += umin / flen;
                flushseg(o, k0, k, vmin, lane);
                return;
            }
            if (k != N - 1) break;
        }
        rnext = 0.5f;
        vn1 = dfetch(vnx, k);
    }
}

// ===================== FUSED-BARRIER kernel ==================================
// No flags, no grid barrier: every cross-wave dependency rides on per-element
// {data,seq} atoms. Buffers double-buffered by iteration parity.
//
// Dependency proofs (point-to-point chase, each wave in-order):
//  * WAR on ytg[P] (read at row it, rewritten at column it+2): column it+2
//    needs xwg tag it+1 from ALL waves, stored at rows it+1, each after that
//    wave's row-it ytg read. Safe.
//  * WAR on xwg[P]: a wave's row it+2 store needs its column it+2 poll (xwg
//    tag it+2 from ALL), stored at rows it+1, after column it+1, after row it,
//    after column it's read of xwg[P]. Safe.
//  * Decision agreement: during any wave's accs[(it-1)&1] poll (tag>=it) no
//    slot can exceed tag it (an it+2 store needs ALL waves past their column
//    it+1 poll, hence past this poll) -> all waves observe the identical
//    256-value set -> identical grid-max -> identical break. No divergence.
//  * Speculative column phase before a break writes only p (dead) and ytg
//    (dead: all waves break together). Safe.
__global__ __launch_bounds__(NT) void tv2d_fused(const float* __restrict__ X,
                                                 float* __restrict__ out,
                                                 u64* __restrict__ ytg,   // [2][N][N] tagged
                                                 u64* __restrict__ xwg,   // [2][N][N] tagged
                                                 u64* __restrict__ accs)  // [2][N] stride-2 slots
{
    const int lane = threadIdx.x;
    const int b = blockIdx.x;

    Dist p = {0.f, 0.f, 0.f, 0.f};
    Dist q = {0.f, 0.f, 0.f, 0.f};
    Dist xout = {0.f, 0.f, 0.f, 0.f};

    for (int it = 0; it < MAXIT; ++it) {
        // ---- column phase: y[:,b] = prox(x[:,b] + p); p = v - y ----
        Dist v, o;
        if (it == 0) {
            gload_col(X, b, lane, v.r0, v.r1, v.r2, v.r3);
        } else {
            pollcol(xwg + (size_t)((it - 1) & 1) * (N * N), b, (unsigned)it, lane, v);
        }
        v.r0 += p.r0;  v.r1 += p.r1;  v.r2 += p.r2;  v.r3 += p.r3;

        // early-issue the decision probe (acc of it-1, tag >= it); consumed
        // after the scan -> the L3 round trip hides under the scan.
        const u64* ab = accs + (size_t)((it - 1) & 1) * (N * 2);
        const u64 *qa0 = ab + (size_t)lane * 2,        *qa1 = ab + (size_t)(lane + 64) * 2,
                  *qa2 = ab + (size_t)(lane + 128) * 2, *qa3 = ab + (size_t)(lane + 192) * 2;
        u64 a0 = 0, a1 = 0, a2 = 0, a3 = 0;
        if (it >= 1) {
            asm volatile("global_load_dwordx2 %0, %4, off sc0 sc1\n\t"
                         "global_load_dwordx2 %1, %5, off sc0 sc1\n\t"
                         "global_load_dwordx2 %2, %6, off sc0 sc1\n\t"
                         "global_load_dwordx2 %3, %7, off sc0 sc1"
                         : "=&v"(a0), "=&v"(a1), "=&v"(a2), "=&v"(a3)
                         : "v"(qa0), "v"(qa1), "v"(qa2), "v"(qa3)
                         : "memory");
        }

        tv1d_scan(v, o, lane);
        p.r0 = v.r0 - o.r0;  p.r1 = v.r1 - o.r1;
        p.r2 = v.r2 - o.r2;  p.r3 = v.r3 - o.r3;

        // ---- decision for iteration it-1 (before row it) ----
        if (it >= 1) {
            asm volatile("s_waitcnt vmcnt(0)" ::: "memory");
            const unsigned seq = (unsigned)it;
            int spin = 0;
            for (;;) {
                const bool ok = ((unsigned)a0 >= seq) & ((unsigned)a1 >= seq) &
                                ((unsigned)a2 >= seq) & ((unsigned)a3 >= seq);
                if (__all((int)ok)) break;
                if (__builtin_expect(++spin > POLLBUDGET, 0)) break;  // hang-proof
                a0 = ald(qa0); a1 = ald(qa1); a2 = ald(qa2); a3 = ald(qa3);
            }
            unsigned ma = (unsigned)(a0 >> 32), mb = (unsigned)(a1 >> 32);
            unsigned mc = (unsigned)(a2 >> 32), md = (unsigned)(a3 >> 32);
            ma = ma > mb ? ma : mb;  mc = mc > md ? mc : md;  ma = ma > mc ? ma : mc;
            const unsigned gm = wredmax(ma);          // uint order == float order (>=0)
            if (__uint_as_float(gm) < TOL) break;     // xout holds x2(it-1)
        }

        // publish y column as tagged yT row (coalesced, fire-and-forget)
        storerow(ytg + (size_t)(it & 1) * (N * N), b, (unsigned)(it + 1), o, lane);

        // ---- row phase: x2[b,:] = prox(y[b,:] + q); q = w - x2 ----
        Dist yv, w, o2;
        pollcol(ytg + (size_t)(it & 1) * (N * N), b, (unsigned)(it + 1), lane, yv);
        w.r0 = yv.r0 + q.r0;
        w.r1 = yv.r1 + q.r1;
        w.r2 = yv.r2 + q.r2;
        w.r3 = yv.r3 + q.r3;
        tv1d_scan(w, o2, lane);
        q.r0 = w.r0 - o2.r0;  q.r1 = w.r1 - o2.r1;
        q.r2 = w.r2 - o2.r2;  q.r3 = w.r3 - o2.r3;
        xout = o2;

        float am = fmaxf(fmaxf(fabsf(yv.r0 - o2.r0), fabsf(yv.r1 - o2.r1)),
                         fmaxf(fabsf(yv.r2 - o2.r2), fabsf(yv.r3 - o2.r3)));
        const unsigned amu = wredmax(__float_as_uint(am));

        if (it < MAXIT - 1) {
            storerow(xwg + (size_t)(it & 1) * (N * N), b, (unsigned)(it + 1), o2, lane);
            if (lane == 0)
                ast((u64*)(accs + (size_t)(it & 1) * (N * 2)) + (size_t)b * 2,
                    ((u64)amu << 32) | (u64)(unsigned)(it + 1));
        }
    }

    // final untagged output row (row-major), coalesced
    float* xr = out + (size_t)b * N;
    xr[lane]       = xout.r0;
    xr[lane + 64]  = xout.r1;
    xr[lane + 128] = xout.r2;
    xr[lane + 192] = xout.r3;
}

// ===================== FALLBACK: verified R3 kernel (204 µs) =================
template <bool WANT>
__device__ __forceinline__ unsigned wavebar(u64* slots, unsigned seq,
                                            unsigned payload, int line, int lane)
{
    __builtin_amdgcn_s_waitcnt(0);
    __hip_atomic_store(&slots[line * SLOTSTRIDE],
                       ((u64)payload << 32) | (u64)seq,
                       __ATOMIC_RELAXED, __HIP_MEMORY_SCOPE_AGENT);
    auto ld = [&](int i) {
        return __hip_atomic_load(&slots[i * SLOTSTRIDE],
                                 __ATOMIC_RELAXED, __HIP_MEMORY_SCOPE_AGENT);
    };
    u64 f0 = ld(lane), f1 = ld(lane + 64), f2 = ld(lane + 128), f3 = ld(lane + 192);
    for (;;) {
        u64 g0 = ld(lane), g1 = ld(lane + 64), g2 = ld(lane + 128), g3 = ld(lane + 192);
        const bool ok = ((unsigned)f0 >= seq) & ((unsigned)f1 >= seq) &
                        ((unsigned)f2 >= seq) & ((unsigned)f3 >= seq);
        if (__all((int)ok)) break;
        f0 = g0; f1 = g1; f2 = g2; f3 = g3;
    }
    unsigned ga = 0u;
    if (WANT) {
        unsigned a = (unsigned)(f0 >> 32), b = (unsigned)(f1 >> 32);
        unsigned c = (unsigned)(f2 >> 32), d = (unsigned)(f3 >> 32);
        a = a > b ? a : b;  c = c > d ? c : d;  a = a > c ? a : c;
        ga = wredmax(a);
    }
    return ga;
}

__global__ __launch_bounds__(NT) void tv2d_coop(const float* __restrict__ X,
                                                float* __restrict__ xw,
                                                float* __restrict__ yt,
                                                u64* __restrict__ slots)
{
    const int lane = threadIdx.x;
    const int b = blockIdx.x;

    Dist p = {0.f, 0.f, 0.f, 0.f};
    Dist q = {0.f, 0.f, 0.f, 0.f};
    unsigned accprev = 0u;

    for (int it = 0; it < MAXIT; ++it) {
        const float* xs = (it == 0) ? X : xw;
        Dist v, o;
        gload_col(xs, b, lane, v.r0, v.r1, v.r2, v.r3);
        v.r0 += p.r0;  v.r1 += p.r1;  v.r2 += p.r2;  v.r3 += p.r3;
        tv1d_scan(v, o, lane);
        p.r0 = v.r0 - o.r0;  p.r1 = v.r1 - o.r1;
        p.r2 = v.r2 - o.r2;  p.r3 = v.r3 - o.r3;
        float* yr = yt + b * N;
        gstore(yr + lane,       o.r0);
        gstore(yr + lane + 64,  o.r1);
        gstore(yr + lane + 128, o.r2);
        gstore(yr + lane + 192, o.r3);
        wavebar<false>(slots, 2u * (unsigned)it + 1u, accprev, b, lane);

        Dist yv, w, o2;
        gload_col(yt, b, lane, yv.r0, yv.r1, yv.r2, yv.r3);
        w.r0 = yv.r0 + q.r0;
        w.r1 = yv.r1 + q.r1;
        w.r2 = yv.r2 + q.r2;
        w.r3 = yv.r3 + q.r3;
        tv1d_scan(w, o2, lane);
        float d0 = yv.r0 - o2.r0;
        float d1 = yv.r1 - o2.r1;
        float d2 = yv.r2 - o2.r2;
        float d3 = yv.r3 - o2.r3;
        q.r0 = w.r0 - o2.r0;  q.r1 = w.r1 - o2.r1;
        q.r2 = w.r2 - o2.r2;  q.r3 = w.r3 - o2.r3;
        float* xr = xw + b * N;
        gstore(xr + lane,       o2.r0);
        gstore(xr + lane + 64,  o2.r1);
        gstore(xr + lane + 128, o2.r2);
        gstore(xr + lane + 192, o2.r3);

        float am = fmaxf(fmaxf(fabsf(d0), fabsf(d1)), fmaxf(fabsf(d2), fabsf(d3)));
        const unsigned amu = wredmax(__float_as_uint(am));

        if (it == MAXIT - 1) break;

        const unsigned ga = wavebar<true>(slots, 2u * (unsigned)it + 2u, amu, b, lane);
        if (__uint_as_float(ga) < TOL) break;
        accprev = amu;
    }
}

extern "C" void kernel_launch(void* const* d_in, const int* in_sizes, int n_in,
                              void* d_out, int out_size, void* d_ws, size_t ws_size,
                              hipStream_t stream) {
    const float* X = (const float*)d_in[0];
    float* xw = (float*)d_out;

    const size_t need = (size_t)4 * N * N * sizeof(u64)      // ytg[2] + xwg[2]
                      + (size_t)2 * N * 2 * sizeof(u64);     // accs[2], stride-2 slots
    if (ws_size >= need) {
        u64* ytg  = (u64*)d_ws;
        u64* xwg  = ytg + (size_t)2 * N * N;
        u64* accs = xwg + (size_t)2 * N * N;
        (void)hipMemsetAsync(d_ws, 0, need, stream);         // tags start at 1 -> 0 is "empty"
        void* args[] = { (void*)&X, (void*)&xw, (void*)&ytg, (void*)&xwg, (void*)&accs };
        (void)hipLaunchCooperativeKernel((void*)tv2d_fused, dim3(NB), dim3(NT), args, 0, stream);
    } else {
        float* yt = (float*)d_ws;
        u64* slots = (u64*)((char*)d_ws + (size_t)N * N * sizeof(float));
        (void)hipMemsetAsync((void*)slots, 0, N * SLOTSTRIDE * sizeof(u64), stream);
        void* args[] = { (void*)&X, (void*)&xw, (void*)&yt, (void*)&slots };
        (void)hipLaunchCooperativeKernel((void*)tv2d_coop, dim3(NB), dim3(NT), args, 0, stream);
    }
}

// Round 6
// 271.985 us; speedup vs baseline: 1.0602x; 1.0602x over previous
//
#include <hip/hip_runtime.h>

#define N 256
#define NB 256                // one block per LINE (one wave per block, one block per CU)
#define NT 64                 // single wave
#define LAM 0.05f             // step = ALPHA/2
#define TWOLAM (2.0f * LAM)
#define FOURLAM (4.0f * LAM)
#define MAXIT 35
#define TOL 0.01f
#define SLOTSTRIDE 2          // 16 B per line slot
#define POLLBUDGET (1 << 17)  // hang-proofing: bug -> bad data, never a dead container

typedef unsigned long long u64;

// broadcast-read one lane's register (lane index is wave-uniform -> v_readlane)
__device__ __forceinline__ float rlane(float v, int lane) {
    return __int_as_float(__builtin_amdgcn_readlane(__float_as_int(v), lane));
}

// agent-scope (L2-bypassing) accesses for cross-wave-communicated arrays.
__device__ __forceinline__ void gstore(float* p, float v) {
    __hip_atomic_store(p, v, __ATOMIC_RELAXED, __HIP_MEMORY_SCOPE_AGENT);
}
__device__ __forceinline__ u64 ald(const u64* p) {
    return __hip_atomic_load(p, __ATOMIC_RELAXED, __HIP_MEMORY_SCOPE_AGENT);
}
__device__ __forceinline__ void ast(u64* p, u64 v) {
    __hip_atomic_store(p, v, __ATOMIC_RELAXED, __HIP_MEMORY_SCOPE_AGENT);
}

// Scattered COLUMN read of a row-major float matrix (X / xw).
__device__ __forceinline__ void gload_col(const float* mat, int c, int lane, float& a,
                                          float& b, float& d, float& e) {
    const float* p0 = mat + (size_t)lane * N + c;
    const float* p1 = p0 + 64 * N;
    const float* p2 = p0 + 128 * N;
    const float* p3 = p0 + 192 * N;
    asm volatile("global_load_dword %0, %4, off sc0 sc1\n\t"
                 "global_load_dword %1, %5, off sc0 sc1\n\t"
                 "global_load_dword %2, %6, off sc0 sc1\n\t"
                 "global_load_dword %3, %7, off sc0 sc1\n\t"
                 "s_waitcnt vmcnt(0)"
                 : "=&v"(a), "=&v"(b), "=&v"(d), "=&v"(e)
                 : "v"(p0), "v"(p1), "v"(p2), "v"(p3)
                 : "memory");
}

// 256-float line distributed over the wave: element k lives in lane (k&63), reg (k>>6)
struct Dist { float r0, r1, r2, r3; };

// branchless fetch: 4 independent readlanes + 2 uniform selects
__device__ __forceinline__ float dfetch(const Dist& d, int k) {
    const int lane = k & 63;
    const int sel = k >> 6;
    float a = rlane(d.r0, lane);
    float b = rlane(d.r1, lane);
    float c = rlane(d.r2, lane);
    float e = rlane(d.r3, lane);
    float ab = (sel & 1) ? b : a;
    float ce = (sel & 1) ? e : c;
    return (sel & 2) ? ce : ab;
}

// O(1) segment flush: o[j] = val for j in [lo, hi]
__device__ __forceinline__ void flushseg(Dist& o, int lo, int hi, float val, int lane) {
    const unsigned len = (unsigned)(hi - lo);
    const int base = lane - lo;
    o.r0 = ((unsigned)(base      ) <= len) ? val : o.r0;
    o.r1 = ((unsigned)(base + 64 ) <= len) ? val : o.r1;
    o.r2 = ((unsigned)(base + 128) <= len) ? val : o.r2;
    o.r3 = ((unsigned)(base + 192) <= len) ? val : o.r3;
}

// scalar 4-way select of a 64-bit mask (s_cselect_b64)
__device__ __forceinline__ u64 sel4(u64 a, u64 b, u64 c, u64 d, int r) {
    u64 ab = (r & 1) ? b : a;
    u64 cd = (r & 1) ? d : c;
    return (r & 2) ? cd : ab;
}

// full-wave max of nonneg-float-as-uint via DPP ladder; verified bitwise R1-R5.
__device__ __forceinline__ unsigned wredmax(unsigned x) {
    unsigned t;
    t = (unsigned)__builtin_amdgcn_update_dpp(0, (int)x, 0x111, 0xf, 0xf, true); x = x > t ? x : t; // row_shr:1
    t = (unsigned)__builtin_amdgcn_update_dpp(0, (int)x, 0x112, 0xf, 0xf, true); x = x > t ? x : t; // row_shr:2
    t = (unsigned)__builtin_amdgcn_update_dpp(0, (int)x, 0x114, 0xf, 0xf, true); x = x > t ? x : t; // row_shr:4
    t = (unsigned)__builtin_amdgcn_update_dpp(0, (int)x, 0x118, 0xf, 0xf, true); x = x > t ? x : t; // row_shr:8
    t = (unsigned)__builtin_amdgcn_update_dpp(0, (int)x, 0x142, 0xf, 0xf, true); x = x > t ? x : t; // row_bcast:15
    t = (unsigned)__builtin_amdgcn_update_dpp(0, (int)x, 0x143, 0xf, 0xf, true); x = x > t ? x : t; // row_bcast:31
    return (unsigned)__builtin_amdgcn_readlane((int)x, 63);
}

// ---- tagged-data transport (proven correct in R5's full-fused run) ----
// Element = {float bits : high 32, seq : low 32}, one 64-bit atom ->
// tag-implies-data with NO drain, NO flags: the poll IS the load.
__device__ __forceinline__ void pollcol(const u64* m, int c, unsigned seq, int lane, Dist& v) {
    const u64* p0 = m + (size_t)lane * N + c;
    const u64* p1 = p0 + 64 * N;
    const u64* p2 = p0 + 128 * N;
    const u64* p3 = p0 + 192 * N;
    u64 f0 = ald(p0), f1 = ald(p1), f2 = ald(p2), f3 = ald(p3);
    int spin = 0;
    for (;;) {
        u64 g0 = ald(p0), g1 = ald(p1), g2 = ald(p2), g3 = ald(p3);
        const bool ok = ((unsigned)f0 >= seq) & ((unsigned)f1 >= seq) &
                        ((unsigned)f2 >= seq) & ((unsigned)f3 >= seq);
        if (__all((int)ok)) break;
        if (__builtin_expect(++spin > POLLBUDGET, 0)) break;   // hang-proof
        f0 = g0; f1 = g1; f2 = g2; f3 = g3;
    }
    v.r0 = __uint_as_float((unsigned)(f0 >> 32));
    v.r1 = __uint_as_float((unsigned)(f1 >> 32));
    v.r2 = __uint_as_float((unsigned)(f2 >> 32));
    v.r3 = __uint_as_float((unsigned)(f3 >> 32));
}

__device__ __forceinline__ void storerow(u64* m, int row, unsigned seq, const Dist& o, int lane) {
    u64* r = m + (size_t)row * N;
    ast(r + lane,       ((u64)__float_as_uint(o.r0) << 32) | (u64)seq);
    ast(r + lane + 64,  ((u64)__float_as_uint(o.r1) << 32) | (u64)seq);
    ast(r + lane + 128, ((u64)__float_as_uint(o.r2) << 32) | (u64)seq);
    ast(r + lane + 192, ((u64)__float_as_uint(o.r3) << 32) | (u64)seq);
}

// ============================================================================
// Condat's exact 1D TV prox (verified structure — UNCHANGED since the 213 µs
// kernel). R1 lesson: with 1 wave/SIMD, program order == critical path; no
// speculative work ahead of the un/ux -> compare -> branch chain.
__device__ void tv1d_scan(const Dist& v, Dist& o, const int lane)
{
    const float lam = LAM, mlam = -LAM, twolam = TWOLAM;

    Dist vnx;                                    // vnx[j] = v[j+1] for j<255; vnx[255] = v[255]
    {
        float a0 = __shfl_down(v.r0, 1), a1 = __shfl_down(v.r1, 1);
        float a2 = __shfl_down(v.r2, 1), a3 = __shfl_down(v.r3, 1);
        const bool hi = (lane == 63);
        vnx.r0 = hi ? rlane(v.r1, 0) : a0;
        vnx.r1 = hi ? rlane(v.r2, 0) : a1;
        vnx.r2 = hi ? rlane(v.r3, 0) : a2;
        vnx.r3 = hi ? v.r3 : a3;
    }
    Dist d;
    d.r0 = vnx.r0 - v.r0;  d.r1 = vnx.r1 - v.r1;
    d.r2 = vnx.r2 - v.r2;  d.r3 = vnx.r3 - v.r3;
    const unsigned lambits = __float_as_uint(lam);
    Dist sl;                                     // sl[j] = sign(d[j]) * lam
    sl.r0 = __uint_as_float((__float_as_uint(d.r0) & 0x80000000u) | lambits);
    sl.r1 = __uint_as_float((__float_as_uint(d.r1) & 0x80000000u) | lambits);
    sl.r2 = __uint_as_float((__float_as_uint(d.r2) & 0x80000000u) | lambits);
    sl.r3 = __uint_as_float((__float_as_uint(d.r3) & 0x80000000u) | lambits);
    Dist slp;                                    // slp[j] = sl[j-1], slp[0] = 0
    {
        float b0 = __shfl_up(sl.r0, 1), b1 = __shfl_up(sl.r1, 1);
        float b2 = __shfl_up(sl.r2, 1), b3 = __shfl_up(sl.r3, 1);
        const bool lo = (lane == 0);
        slp.r0 = lo ? 0.0f : b0;
        slp.r1 = lo ? rlane(sl.r0, 63) : b1;
        slp.r2 = lo ? rlane(sl.r1, 63) : b2;
        slp.r3 = lo ? rlane(sl.r2, 63) : b3;
    }
    Dist e, g;                                   // e[j]=v+sl-slp; g[j]=v-lam-slp
    {
        float t0 = v.r0 - slp.r0, t1 = v.r1 - slp.r1, t2 = v.r2 - slp.r2, t3 = v.r3 - slp.r3;
        e.r0 = t0 + sl.r0;  e.r1 = t1 + sl.r1;  e.r2 = t2 + sl.r2;  e.r3 = t3 + sl.r3;
        g.r0 = t0 - lam;    g.r1 = t1 - lam;    g.r2 = t2 - lam;    g.r3 = t3 - lam;
    }
    const u64 S0 = __ballot(d.r0 < 0.0f);
    const u64 S1 = __ballot(d.r1 < 0.0f);
    const u64 S2 = __ballot(d.r2 < 0.0f);
    const u64 S3 = __ballot(d.r3 < 0.0f);
    const u64 B20 = __ballot(fabsf(d.r0) > TWOLAM);
    const u64 B21 = __ballot(fabsf(d.r1) > TWOLAM);
    const u64 B22 = __ballot(fabsf(d.r2) > TWOLAM);
    const u64 B23 = __ballot(fabsf(d.r3) > TWOLAM);
    const u64 B40 = __ballot(fabsf(d.r0) > FOURLAM);
    const u64 B41 = __ballot(fabsf(d.r1) > FOURLAM);
    const u64 B42 = __ballot(fabsf(d.r2) > FOURLAM);
    const u64 B43 = __ballot(fabsf(d.r3) > FOURLAM);
    const u64 Sp0 = (S0 << 1);
    const u64 Sp1 = (S1 << 1) | (S0 >> 63);
    const u64 Sp2 = (S2 << 1) | (S1 >> 63);
    const u64 Sp3 = (S3 << 1) | (S2 >> 63);
    const u64 NF0 = ~(B40 | (B20 & ~(S0 ^ Sp0)));
    const u64 NF1 = ~(B41 | (B21 & ~(S1 ^ Sp1)));
    const u64 NF2 = ~(B42 | (B22 & ~(S2 ^ Sp2)));
    const u64 NF3 = ~((B43 | (B23 & ~(S3 ^ Sp3))) & 0x7FFFFFFFFFFFFFFFull);
    const u64 FNn0 = (S0 & B20) | (~S0 & B40);
    const u64 FNn1 = (S1 & B21) | (~S1 & B41);
    const u64 FNn2 = (S2 & B22) | (~S2 & B42);
    const u64 FNn3 = (S3 & B23) | (~S3 & B43);
    const u64 FNp0 = (~S0 & B20) | (S0 & B40);
    const u64 FNp1 = (~S1 & B21) | (S1 & B41);
    const u64 FNp2 = (~S2 & B22) | (S2 & B42);
    const u64 FNp3 = (~S3 & B23) | (S3 & B43);
    const int initFF = (int)(B40 & 1ull);

    auto firstnf = [&](int jmin) -> int {
        const int w = jmin >> 6;
        u64 m = sel4(NF0, NF1, NF2, NF3, w) >> (jmin & 63);
        if (m) return jmin + (int)__builtin_ctzll(m);
        u64 m1 = (w < 1) ? NF1 : 0ull;
        u64 m2 = (w < 2) ? NF2 : 0ull;
        if (m1) return 64 + (int)__builtin_ctzll(m1);
        if (m2) return 128 + (int)__builtin_ctzll(m2);
        return 192 + (int)__builtin_ctzll(NF3);
    };

    auto trigbit = [&](int kk, int neg) -> int {
        const int w = kk >> 6;
        const u64 m = neg ? sel4(FNn0, FNn1, FNn2, FNn3, w)
                          : sel4(FNp0, FNp1, FNp2, FNp3, w);
        return (int)((m >> (kk & 63)) & 1ull);
    };

    int k = 0, k0 = 0, km = 0, kp = 0;
    float umin = lam, umax = mlam;
    const float v0 = rlane(v.r0, 0);
    float vmin = v0 - lam, vmax = v0 + lam;
    float flen = 1.0f;
    float rnext = 0.5f;
    float vn1 = rlane(vnx.r0, 0);

    auto fastfwd = [&]() {
        const int K1 = firstnf(k + 1);
        const int sneg = (int)((sel4(S0, S1, S2, S3, k >> 6) >> (k & 63)) & 1ull);
        flushseg(o, k, k, sneg ? vmin : vmax, lane);
        if (K1 > k + 1) {
            const int lo = k + 1;
            const unsigned len = (unsigned)(K1 - 1 - lo);
            const int base = lane - lo;
            o.r0 = ((unsigned)(base      ) <= len) ? e.r0 : o.r0;
            o.r1 = ((unsigned)(base + 64 ) <= len) ? e.r1 : o.r1;
            o.r2 = ((unsigned)(base + 128) <= len) ? e.r2 : o.r2;
            o.r3 = ((unsigned)(base + 192) <= len) ? e.r3 : o.r3;
        }
        k = K1; k0 = K1; km = K1; kp = K1;
        vmin = dfetch(g, K1);
        vmax = vmin + twolam;
        umin = lam; umax = mlam;
        flen = 1.0f; rnext = 0.5f;
        vn1 = dfetch(vnx, K1);
    };

    auto do_step = [&]() {
        const float un = umin + vn1 - vmin;
        const float ux = umax + vn1 - vmax;
        const bool neg = un < mlam;
        const bool pos = ux > lam;
        const int wn = (k + 1) >> 6, bn = (k + 1) & 63;
        const int tn = (int)((sel4(FNn0, FNn1, FNn2, FNn3, wn) >> bn) & 1ull);
        const int tp = (int)((sel4(FNp0, FNp1, FNp2, FNp3, wn) >> bn) & 1ull);
        if (__builtin_expect((int)(neg | pos), 1)) {          // JUMP
            const float fval = neg ? vmin : vmax;
            const int   fhi  = neg ? km : kp;
            flushseg(o, k0, fhi, fval, lane);
            const int k0n = fhi + 1;
            float vstar;
            int trig;
            if (__builtin_expect((int)(k0n <= k), 0)) {       // rewind (rare)
                vstar = dfetch(v, k0n);
                trig = trigbit(k0n, (int)neg);
            } else {
                vstar = vn1;
                trig = neg ? tn : tp;
            }
            k = k0n; k0 = k0n; km = k0n; kp = k0n;
            vmin = neg ? vstar : vstar - twolam;
            vmax = vmin + twolam;
            umin = lam; umax = mlam;
            flen = 1.0f; rnext = 0.5f;
            if (k < N - 1 && trig) {
                fastfwd();
            } else {
                vn1 = dfetch(vnx, k);
            }
        } else {                                              // no jump (predicated)
            k++;
            const float r = rnext;
            flen += 1.0f;
            const bool cmin = (un >= lam);
            const bool cmax = (ux <= mlam);
            vmin = cmin ? fmaf(un - lam, r, vmin) : vmin;
            km   = cmin ? k : km;
            umin = cmin ? lam : un;
            vmax = cmax ? fmaf(ux + lam, r, vmax) : vmax;
            kp   = cmax ? k : kp;
            umax = cmax ? mlam : ux;
            vn1 = dfetch(vnx, k);
            rnext = __builtin_amdgcn_rcpf(flen + 1.0f);
        }
    };

    if (initFF) fastfwd();

    for (;;) {
        while (k < N - 1) {
            do_step();
            if (k >= N - 1) break;
            do_step();
        }
        for (;;) {
            if (umin < 0.0f) {
                flushseg(o, k0, km, vmin, lane);
                k0 = km + 1;
                if (k0 > N - 1) return;
                km = k = k0;
                vmin = dfetch(v, k0);
                umin = lam;
                umax = vmin + lam - vmax;
                flen = 1.0f;
            } else if (umax > 0.0f) {
                flushseg(o, k0, kp, vmax, lane);
                k0 = kp + 1;
                if (k0 > N - 1) return;
                kp = k = k0;
                vmax = dfetch(v, k0);
                umax = mlam;
                umin = vmax - lam - vmin;
                flen = 1.0f;
            } else {
                vmin += umin / flen;
                flushseg(o, k0, k, vmin, lane);
                return;
            }
            if (k != N - 1) break;
        }
        rnext = 0.5f;
        vn1 = dfetch(vnx, k);
    }
}

// Flag barrier with payload (verbatim-proven R3 wavebar, + spin budget).
template <bool WANT>
__device__ __forceinline__ unsigned wavebar(u64* slots, unsigned seq,
                                            unsigned payload, int line, int lane)
{
    __builtin_amdgcn_s_waitcnt(0);                            // own data stores drained
    __hip_atomic_store(&slots[line * SLOTSTRIDE],
                       ((u64)payload << 32) | (u64)seq,
                       __ATOMIC_RELAXED, __HIP_MEMORY_SCOPE_AGENT);
    auto ld = [&](int i) {
        return __hip_atomic_load(&slots[i * SLOTSTRIDE],
                                 __ATOMIC_RELAXED, __HIP_MEMORY_SCOPE_AGENT);
    };
    u64 f0 = ld(lane), f1 = ld(lane + 64), f2 = ld(lane + 128), f3 = ld(lane + 192);
    int spin = 0;
    for (;;) {
        u64 g0 = ld(lane), g1 = ld(lane + 64), g2 = ld(lane + 128), g3 = ld(lane + 192);
        const bool ok = ((unsigned)f0 >= seq) & ((unsigned)f1 >= seq) &
                        ((unsigned)f2 >= seq) & ((unsigned)f3 >= seq);
        if (__all((int)ok)) break;
        if (__builtin_expect(++spin > POLLBUDGET, 0)) break;  // hang-proof
        f0 = g0; f1 = g1; f2 = g2; f3 = g3;
    }
    unsigned ga = 0u;
    if (WANT) {
        unsigned a = (unsigned)(f0 >> 32), b = (unsigned)(f1 >> 32);
        unsigned c = (unsigned)(f2 >> 32), d = (unsigned)(f3 >> 32);
        a = a > b ? a : b;  c = c > d ? c : d;  a = a > c ? a : c;
        ga = wredmax(a);
    }
    return ga;
}

// ===================== HALF-FUSED kernel =====================================
// Column->row boundary: tagged yT transport (storerow + pollcol) — removes
// barrier 1's drain+flag+poll+load chain (4 serialized L3 trips -> 1).
// Row->column boundary: R3's proven flag barrier ONCE per iteration, carrying
// this iteration's acc payload (exact: no wave can reach barrier it+2 while
// another polls it+1, since its column-(it+1) pollcol needs the slow wave's
// ytg tag it+2, stored only after that wave exits barrier it+1).
// WAR on the single ytg buffer: reads (row it) precede each wave's barrier
// arrival; rewrites (column it+1) follow barrier exit. Safe.
// WAR/RAW on plain-float xw: reads (column it+1, after barrier it) vs writes
// (row it before barrier / row it+1 after all column-(it+1) ytg stores, which
// follow each wave's xw read). Safe.
__global__ __launch_bounds__(NT) void tv2d_half(const float* __restrict__ X,
                                                float* __restrict__ xw,     // = d_out (row-major x2)
                                                u64* __restrict__ ytg,      // [N][N] tagged yT
                                                u64* __restrict__ slots)
{
    const int lane = threadIdx.x;
    const int b = blockIdx.x;

    Dist p = {0.f, 0.f, 0.f, 0.f};
    Dist q = {0.f, 0.f, 0.f, 0.f};

    for (int it = 0; it < MAXIT; ++it) {
        // ---- column phase: y[:,b] = prox(x[:,b] + p); p = v - y ----
        const float* xs = (it == 0) ? X : xw;
        Dist v, o;
        gload_col(xs, b, lane, v.r0, v.r1, v.r2, v.r3);
        v.r0 += p.r0;  v.r1 += p.r1;  v.r2 += p.r2;  v.r3 += p.r3;
        tv1d_scan(v, o, lane);
        p.r0 = v.r0 - o.r0;  p.r1 = v.r1 - o.r1;
        p.r2 = v.r2 - o.r2;  p.r3 = v.r3 - o.r3;
        storerow(ytg, b, (unsigned)(it + 1), o, lane);   // tagged, fire-and-forget

        // ---- row phase: x2[b,:] = prox(y[b,:] + q); q = w - x2 ----
        Dist yv, w, o2;
        pollcol(ytg, b, (unsigned)(it + 1), lane, yv);   // sync == load
        w.r0 = yv.r0 + q.r0;
        w.r1 = yv.r1 + q.r1;
        w.r2 = yv.r2 + q.r2;
        w.r3 = yv.r3 + q.r3;
        tv1d_scan(w, o2, lane);
        q.r0 = w.r0 - o2.r0;  q.r1 = w.r1 - o2.r1;
        q.r2 = w.r2 - o2.r2;  q.r3 = w.r3 - o2.r3;
        float* xr = xw + (size_t)b * N;                  // row-major output (coalesced)
        gstore(xr + lane,       o2.r0);
        gstore(xr + lane + 64,  o2.r1);
        gstore(xr + lane + 128, o2.r2);
        gstore(xr + lane + 192, o2.r3);

        float am = fmaxf(fmaxf(fabsf(yv.r0 - o2.r0), fabsf(yv.r1 - o2.r1)),
                         fmaxf(fabsf(yv.r2 - o2.r2), fabsf(yv.r3 - o2.r3)));
        const unsigned amu = wredmax(__float_as_uint(am));

        if (it == MAXIT - 1) break;                      // xw complete, nothing further read

        // ---- single barrier per iteration: sync + exact convergence decision ----
        const unsigned ga = wavebar<true>(slots, (unsigned)(it + 1), amu, b, lane);
        if (__uint_as_float(ga) < TOL) break;            // xw holds x2(it)
    }
}

// ===================== FALLBACK: verified R3 kernel (204 µs) =================
__global__ __launch_bounds__(NT) void tv2d_coop(const float* __restrict__ X,
                                                float* __restrict__ xw,
                                                float* __restrict__ yt,
                                                u64* __restrict__ slots)
{
    const int lane = threadIdx.x;
    const int b = blockIdx.x;

    Dist p = {0.f, 0.f, 0.f, 0.f};
    Dist q = {0.f, 0.f, 0.f, 0.f};
    unsigned accprev = 0u;

    for (int it = 0; it < MAXIT; ++it) {
        const float* xs = (it == 0) ? X : xw;
        Dist v, o;
        gload_col(xs, b, lane, v.r0, v.r1, v.r2, v.r3);
        v.r0 += p.r0;  v.r1 += p.r1;  v.r2 += p.r2;  v.r3 += p.r3;
        tv1d_scan(v, o, lane);
        p.r0 = v.r0 - o.r0;  p.r1 = v.r1 - o.r1;
        p.r2 = v.r2 - o.r2;  p.r3 = v.r3 - o.r3;
        float* yr = yt + b * N;
        gstore(yr + lane,       o.r0);
        gstore(yr + lane + 64,  o.r1);
        gstore(yr + lane + 128, o.r2);
        gstore(yr + lane + 192, o.r3);
        wavebar<false>(slots, 2u * (unsigned)it + 1u, accprev, b, lane);

        Dist yv, w, o2;
        gload_col(yt, b, lane, yv.r0, yv.r1, yv.r2, yv.r3);
        w.r0 = yv.r0 + q.r0;
        w.r1 = yv.r1 + q.r1;
        w.r2 = yv.r2 + q.r2;
        w.r3 = yv.r3 + q.r3;
        tv1d_scan(w, o2, lane);
        float d0 = yv.r0 - o2.r0;
        float d1 = yv.r1 - o2.r1;
        float d2 = yv.r2 - o2.r2;
        float d3 = yv.r3 - o2.r3;
        q.r0 = w.r0 - o2.r0;  q.r1 = w.r1 - o2.r1;
        q.r2 = w.r2 - o2.r2;  q.r3 = w.r3 - o2.r3;
        float* xr = xw + b * N;
        gstore(xr + lane,       o2.r0);
        gstore(xr + lane + 64,  o2.r1);
        gstore(xr + lane + 128, o2.r2);
        gstore(xr + lane + 192, o2.r3);

        float am = fmaxf(fmaxf(fabsf(d0), fabsf(d1)), fmaxf(fabsf(d2), fabsf(d3)));
        const unsigned amu = wredmax(__float_as_uint(am));

        if (it == MAXIT - 1) break;

        const unsigned ga = wavebar<true>(slots, 2u * (unsigned)it + 2u, amu, b, lane);
        if (__uint_as_float(ga) < TOL) break;
        accprev = amu;
    }
}

extern "C" void kernel_launch(void* const* d_in, const int* in_sizes, int n_in,
                              void* d_out, int out_size, void* d_ws, size_t ws_size,
                              hipStream_t stream) {
    const float* X = (const float*)d_in[0];
    float* xw = (float*)d_out;

    const size_t need = (size_t)N * N * sizeof(u64)          // ytg
                      + (size_t)N * SLOTSTRIDE * sizeof(u64);// slots
    if (ws_size >= need) {
        u64* ytg   = (u64*)d_ws;
        u64* slots = ytg + (size_t)N * N;
        (void)hipMemsetAsync(d_ws, 0, need, stream);         // tags/seqs start at 0
        void* args[] = { (void*)&X, (void*)&xw, (void*)&ytg, (void*)&slots };
        (void)hipLaunchCooperativeKernel((void*)tv2d_half, dim3(NB), dim3(NT), args, 0, stream);
    } else {
        float* yt = (float*)d_ws;
        u64* slots = (u64*)((char*)d_ws + (size_t)N * N * sizeof(float));
        (void)hipMemsetAsync((void*)slots, 0, N * SLOTSTRIDE * sizeof(u64), stream);
        void* args[] = { (void*)&X, (void*)&xw, (void*)&yt, (void*)&slots };
        (void)hipLaunchCooperativeKernel((void*)tv2d_coop, dim3(NB), dim3(NT), args, 0, stream);
    }
}